// Round 1
// baseline (446.764 us; speedup 1.0000x reference)
//
#include <hip/hip_runtime.h>
#include <math.h>

#define B_  32
#define C_  512
#define CR_ 32
#define HW_ 4096
#define EPSV 1e-5f

// ---------------- Kernel 1: per-(b,c) sum/sumsq + attention logits ----------------
// Grid: (C/16, B). Each block: 16 channels, full HW. Each thread owns 16 s-values.
__global__ __launch_bounds__(256) void k1_stats_logits(
    const float* __restrict__ x, const float* __restrict__ w_mask,
    float* __restrict__ sums, float* __restrict__ sqs, float* __restrict__ logits)
{
    __shared__ float ls[4], lq[4];
    const int b  = blockIdx.y;
    const int c0 = blockIdx.x * 16;
    const int t  = threadIdx.x;
    const int lane = t & 63, wid = t >> 6;

    float acc[16];
#pragma unroll
    for (int j = 0; j < 16; ++j) acc[j] = 0.f;

    for (int cc = 0; cc < 16; ++cc) {
        const int c = c0 + cc;
        const float wc = w_mask[c];
        const float4* px = reinterpret_cast<const float4*>(x + (size_t)(b * C_ + c) * HW_);
        float s = 0.f, q = 0.f;
#pragma unroll
        for (int k = 0; k < 4; ++k) {
            const float4 v = px[t * 4 + k];
            s += v.x + v.y + v.z + v.w;
            q += v.x*v.x + v.y*v.y + v.z*v.z + v.w*v.w;
            acc[k*4+0] += wc * v.x;
            acc[k*4+1] += wc * v.y;
            acc[k*4+2] += wc * v.z;
            acc[k*4+3] += wc * v.w;
        }
#pragma unroll
        for (int o = 32; o > 0; o >>= 1) {
            s += __shfl_down(s, o);
            q += __shfl_down(q, o);
        }
        __syncthreads();                     // protect ls/lq from previous iter's reads
        if (lane == 0) { ls[wid] = s; lq[wid] = q; }
        __syncthreads();
        if (t == 0) {
            sums[b * C_ + c] = ls[0] + ls[1] + ls[2] + ls[3];
            sqs [b * C_ + c] = lq[0] + lq[1] + lq[2] + lq[3];
        }
    }
    // scatter this chunk's logit contribution (16 chunks per (b,s) -> atomics)
    float* lg = logits + (size_t)b * HW_ + t * 16;
#pragma unroll
    for (int j = 0; j < 16; ++j) atomicAdd(lg + j, acc[j]);
}

// ---------------- Kernel 2: softmax over HW per batch ----------------
__global__ __launch_bounds__(256) void k2_softmax(
    const float* __restrict__ logits, float* __restrict__ attn)
{
    __shared__ float l4[4];
    __shared__ float sM, sZ;
    const int b = blockIdx.x, t = threadIdx.x;
    const int lane = t & 63, wid = t >> 6;
    const float4* pl = reinterpret_cast<const float4*>(logits + (size_t)b * HW_);
    float4 v[4];
    float mx = -3.0e38f;
#pragma unroll
    for (int k = 0; k < 4; ++k) {
        v[k] = pl[t * 4 + k];
        mx = fmaxf(mx, fmaxf(fmaxf(v[k].x, v[k].y), fmaxf(v[k].z, v[k].w)));
    }
#pragma unroll
    for (int o = 32; o > 0; o >>= 1) mx = fmaxf(mx, __shfl_down(mx, o));
    if (lane == 0) l4[wid] = mx;
    __syncthreads();
    if (t == 0) sM = fmaxf(fmaxf(l4[0], l4[1]), fmaxf(l4[2], l4[3]));
    __syncthreads();
    const float M = sM;
    float e[16];
    float sum = 0.f;
#pragma unroll
    for (int k = 0; k < 4; ++k) {
        e[k*4+0] = expf(v[k].x - M);
        e[k*4+1] = expf(v[k].y - M);
        e[k*4+2] = expf(v[k].z - M);
        e[k*4+3] = expf(v[k].w - M);
        sum += e[k*4+0] + e[k*4+1] + e[k*4+2] + e[k*4+3];
    }
#pragma unroll
    for (int o = 32; o > 0; o >>= 1) sum += __shfl_down(sum, o);
    __syncthreads();
    if (lane == 0) l4[wid] = sum;
    __syncthreads();
    if (t == 0) sZ = l4[0] + l4[1] + l4[2] + l4[3];
    __syncthreads();
    const float rz = 1.f / sZ;
    float4* pa = reinterpret_cast<float4*>(attn + (size_t)b * HW_);
#pragma unroll
    for (int k = 0; k < 4; ++k)
        pa[t * 4 + k] = make_float4(e[k*4+0]*rz, e[k*4+1]*rz, e[k*4+2]*rz, e[k*4+3]*rz);
}

// ---------------- Kernel 3: context[b,c] = sum_s x[b,c,s]*attn[b,s] ----------------
__global__ __launch_bounds__(256) void k3_context(
    const float* __restrict__ x, const float* __restrict__ attn, float* __restrict__ ctx)
{
    __shared__ float l4[4];
    const int b = blockIdx.y, c = blockIdx.x, t = threadIdx.x;
    const int lane = t & 63, wid = t >> 6;
    const float4* px = reinterpret_cast<const float4*>(x + (size_t)(b * C_ + c) * HW_);
    const float4* pa = reinterpret_cast<const float4*>(attn + (size_t)b * HW_);
    float s = 0.f;
#pragma unroll
    for (int k = 0; k < 4; ++k) {
        const float4 xv = px[t * 4 + k];
        const float4 av = pa[t * 4 + k];
        s += xv.x*av.x + xv.y*av.y + xv.z*av.z + xv.w*av.w;
    }
#pragma unroll
    for (int o = 32; o > 0; o >>= 1) s += __shfl_down(s, o);
    if (lane == 0) l4[wid] = s;
    __syncthreads();
    if (t == 0) ctx[b * C_ + c] = l4[0] + l4[1] + l4[2] + l4[3];
}

// ---------------- Kernel 4: MLP gate + fold instance-norm stats into (A,D) ----------------
// out = A*x + D with A = g + (1-g)*r, D = -(1-g)*r*m
__global__ __launch_bounds__(256) void k4_mlp(
    const float* __restrict__ ctx, const float* __restrict__ w1, const float* __restrict__ b1,
    const float* __restrict__ ln_g, const float* __restrict__ ln_b,
    const float* __restrict__ w2, const float* __restrict__ b2,
    const float* __restrict__ sums, const float* __restrict__ sqs,
    float* __restrict__ Ab, float* __restrict__ Db)
{
    __shared__ float cs[C_];
    __shared__ float tl[CR_];
    const int b = blockIdx.x, t = threadIdx.x;
    cs[t]       = ctx[b * C_ + t];
    cs[t + 256] = ctx[b * C_ + t + 256];
    __syncthreads();

    // t_i = ctx . w1[i,:] + b1[i]; 8 threads per row
    const int row = t >> 3, sub = t & 7;
    float p = 0.f;
#pragma unroll 8
    for (int k = 0; k < 64; ++k) {
        const int c = sub + (k << 3);
        p += cs[c] * w1[row * C_ + c];
    }
    p += __shfl_down(p, 4, 8);
    p += __shfl_down(p, 2, 8);
    p += __shfl_down(p, 1, 8);
    if (sub == 0) tl[row] = p + b1[row];
    __syncthreads();

    // LayerNorm over CR_ + ReLU
    float tn = 0.f;
    if (t < CR_) {
        float mu = 0.f;
#pragma unroll
        for (int i = 0; i < CR_; ++i) mu += tl[i];
        mu *= (1.f / CR_);
        float var = 0.f;
#pragma unroll
        for (int i = 0; i < CR_; ++i) { const float d = tl[i] - mu; var += d * d; }
        var *= (1.f / CR_);
        tn = (tl[t] - mu) * rsqrtf(var + EPSV) * ln_g[t] + ln_b[t];
        tn = fmaxf(tn, 0.f);
    }
    __syncthreads();
    if (t < CR_) tl[t] = tn;
    __syncthreads();

    // gate + fold instance-norm stats
#pragma unroll
    for (int r = 0; r < 2; ++r) {
        const int c = t + r * 256;
        float g = b2[c];
#pragma unroll
        for (int i = 0; i < CR_; ++i) g += tl[i] * w2[c * CR_ + i];
        g = 1.f / (1.f + expf(-g));
        const float m  = sums[b * C_ + c] * (1.f / HW_);
        const float v  = sqs [b * C_ + c] * (1.f / HW_) - m * m;
        const float rn = rsqrtf(v + EPSV);
        Ab[b * C_ + c] = g + (1.f - g) * rn;
        Db[b * C_ + c] = -(1.f - g) * rn * m;
    }
}

// ---------------- Kernel 5: out = A*x + D ----------------
__global__ __launch_bounds__(256) void k5_apply(
    const float* __restrict__ x, const float* __restrict__ Ab, const float* __restrict__ Db,
    float* __restrict__ out)
{
    const int b = blockIdx.y, c = blockIdx.x, t = threadIdx.x;
    const size_t base = (size_t)(b * C_ + c) * HW_;
    const float a = Ab[b * C_ + c], d = Db[b * C_ + c];
    const float4* px = reinterpret_cast<const float4*>(x + base);
    float4*       po = reinterpret_cast<float4*>(out + base);
#pragma unroll
    for (int k = 0; k < 4; ++k) {
        const float4 v = px[t + 256 * k];
        po[t + 256 * k] = make_float4(fmaf(a, v.x, d), fmaf(a, v.y, d),
                                      fmaf(a, v.z, d), fmaf(a, v.w, d));
    }
}

extern "C" void kernel_launch(void* const* d_in, const int* in_sizes, int n_in,
                              void* d_out, int out_size, void* d_ws, size_t ws_size,
                              hipStream_t stream)
{
    const float* x      = (const float*)d_in[0];
    const float* w_mask = (const float*)d_in[1];
    // d_in[2] = b_mask: constant shift, cancels in softmax
    const float* w1     = (const float*)d_in[3];
    const float* b1     = (const float*)d_in[4];
    const float* ln_g   = (const float*)d_in[5];
    const float* ln_b   = (const float*)d_in[6];
    const float* w2     = (const float*)d_in[7];
    const float* b2     = (const float*)d_in[8];
    float* out = (float*)d_out;

    float* ws     = (float*)d_ws;
    float* sums   = ws;                       // B*C
    float* sqs    = sums   + B_ * C_;         // B*C
    float* logits = sqs    + B_ * C_;         // B*HW
    float* attn   = logits + B_ * HW_;        // B*HW
    float* ctx    = attn   + B_ * HW_;        // B*C
    float* Ab     = ctx    + B_ * C_;         // B*C
    float* Db     = Ab     + B_ * C_;         // B*C

    hipMemsetAsync(logits, 0, (size_t)B_ * HW_ * sizeof(float), stream);
    k1_stats_logits<<<dim3(C_ / 16, B_), 256, 0, stream>>>(x, w_mask, sums, sqs, logits);
    k2_softmax<<<B_, 256, 0, stream>>>(logits, attn);
    k3_context<<<dim3(C_, B_), 256, 0, stream>>>(x, attn, ctx);
    k4_mlp<<<B_, 256, 0, stream>>>(ctx, w1, b1, ln_g, ln_b, w2, b2, sums, sqs, Ab, Db);
    k5_apply<<<dim3(C_, B_), 256, 0, stream>>>(x, Ab, Db, out);
}

// Round 2
// 199.058 us; speedup vs baseline: 2.2444x; 2.2444x over previous
//
#include <hip/hip_runtime.h>
#include <math.h>

#define B_   32
#define C_   512
#define CR_  32
#define HW_  4096
#define NCH  16           // channel chunks
#define CPB  (C_/NCH)     // 32 channels per chunk
#define EPSV 1e-5f

// ---- k1: partial logits. partial[b][ch][s] = sum_{c in chunk} w[c]*x[b,c,s]
// Pure streaming: no LDS, no atomics. Coalesced float4 reads (1KB/wave/instr).
__global__ __launch_bounds__(256) void k1_logits_partial(
    const float* __restrict__ x, const float* __restrict__ w_mask,
    float* __restrict__ partial)
{
    const int b = blockIdx.y, ch = blockIdx.x, t = threadIdx.x;
    const int c0 = ch * CPB;
    float4 a0 = {0,0,0,0}, a1 = {0,0,0,0}, a2 = {0,0,0,0}, a3 = {0,0,0,0};
    for (int cc = 0; cc < CPB; ++cc) {
        const float w = w_mask[c0 + cc];
        const float4* px = reinterpret_cast<const float4*>(x + (size_t)(b * C_ + c0 + cc) * HW_);
        float4 v;
        v = px[t      ]; a0.x += w*v.x; a0.y += w*v.y; a0.z += w*v.z; a0.w += w*v.w;
        v = px[t + 256]; a1.x += w*v.x; a1.y += w*v.y; a1.z += w*v.z; a1.w += w*v.w;
        v = px[t + 512]; a2.x += w*v.x; a2.y += w*v.y; a2.z += w*v.z; a2.w += w*v.w;
        v = px[t + 768]; a3.x += w*v.x; a3.y += w*v.y; a3.z += w*v.z; a3.w += w*v.w;
    }
    float4* pp = reinterpret_cast<float4*>(partial + (size_t)(b * NCH + ch) * HW_);
    pp[t      ] = a0;
    pp[t + 256] = a1;
    pp[t + 512] = a2;
    pp[t + 768] = a3;
}

// ---- k2a: logits[b,s] = sum_ch partial[b][ch][s]
__global__ __launch_bounds__(256) void k2a_reduce(
    const float* __restrict__ partial, float* __restrict__ logits)
{
    const int b = blockIdx.y;
    const int i = blockIdx.x * 256 + threadIdx.x;   // float4 index
    float4 s = {0,0,0,0};
#pragma unroll
    for (int ch = 0; ch < NCH; ++ch) {
        const float4 v = reinterpret_cast<const float4*>(partial + (size_t)(b * NCH + ch) * HW_)[i];
        s.x += v.x; s.y += v.y; s.z += v.z; s.w += v.w;
    }
    reinterpret_cast<float4*>(logits + (size_t)b * HW_)[i] = s;
}

// ---- k2b: softmax over HW per batch
__global__ __launch_bounds__(256) void k2b_softmax(
    const float* __restrict__ logits, float* __restrict__ attn)
{
    __shared__ float l4[4];
    __shared__ float sM, sZ;
    const int b = blockIdx.x, t = threadIdx.x;
    const int lane = t & 63, wid = t >> 6;
    const float4* pl = reinterpret_cast<const float4*>(logits + (size_t)b * HW_);
    float4 v[4];
    float mx = -3.0e38f;
#pragma unroll
    for (int k = 0; k < 4; ++k) {
        v[k] = pl[t + 256 * k];
        mx = fmaxf(mx, fmaxf(fmaxf(v[k].x, v[k].y), fmaxf(v[k].z, v[k].w)));
    }
#pragma unroll
    for (int o = 32; o > 0; o >>= 1) mx = fmaxf(mx, __shfl_down(mx, o));
    if (lane == 0) l4[wid] = mx;
    __syncthreads();
    if (t == 0) sM = fmaxf(fmaxf(l4[0], l4[1]), fmaxf(l4[2], l4[3]));
    __syncthreads();
    const float M = sM;
    float e[16];
    float sum = 0.f;
#pragma unroll
    for (int k = 0; k < 4; ++k) {
        e[k*4+0] = expf(v[k].x - M);
        e[k*4+1] = expf(v[k].y - M);
        e[k*4+2] = expf(v[k].z - M);
        e[k*4+3] = expf(v[k].w - M);
        sum += e[k*4+0] + e[k*4+1] + e[k*4+2] + e[k*4+3];
    }
#pragma unroll
    for (int o = 32; o > 0; o >>= 1) sum += __shfl_down(sum, o);
    __syncthreads();
    if (lane == 0) l4[wid] = sum;
    __syncthreads();
    if (t == 0) sZ = l4[0] + l4[1] + l4[2] + l4[3];
    __syncthreads();
    const float rz = 1.f / sZ;
    float4* pa = reinterpret_cast<float4*>(attn + (size_t)b * HW_);
#pragma unroll
    for (int k = 0; k < 4; ++k)
        pa[t + 256 * k] = make_float4(e[k*4+0]*rz, e[k*4+1]*rz, e[k*4+2]*rz, e[k*4+3]*rz);
}

// ---- k3: context + instance-norm stats in one sweep of x[b,c,:]
__global__ __launch_bounds__(256) void k3_context_stats(
    const float* __restrict__ x, const float* __restrict__ attn,
    float* __restrict__ ctx, float* __restrict__ sums, float* __restrict__ sqs)
{
    __shared__ float ld[12];
    const int b = blockIdx.y, c = blockIdx.x, t = threadIdx.x;
    const int lane = t & 63, wid = t >> 6;
    const float4* px = reinterpret_cast<const float4*>(x + (size_t)(b * C_ + c) * HW_);
    const float4* pa = reinterpret_cast<const float4*>(attn + (size_t)b * HW_);
    float dot = 0.f, sm = 0.f, sq = 0.f;
#pragma unroll
    for (int k = 0; k < 4; ++k) {
        const float4 xv = px[t + 256 * k];
        const float4 av = pa[t + 256 * k];
        dot += xv.x*av.x + xv.y*av.y + xv.z*av.z + xv.w*av.w;
        sm  += xv.x + xv.y + xv.z + xv.w;
        sq  += xv.x*xv.x + xv.y*xv.y + xv.z*xv.z + xv.w*xv.w;
    }
#pragma unroll
    for (int o = 32; o > 0; o >>= 1) {
        dot += __shfl_down(dot, o);
        sm  += __shfl_down(sm, o);
        sq  += __shfl_down(sq, o);
    }
    if (lane == 0) { ld[wid] = dot; ld[4 + wid] = sm; ld[8 + wid] = sq; }
    __syncthreads();
    if (t == 0) {
        ctx [b * C_ + c] = ld[0] + ld[1] + ld[2]  + ld[3];
        sums[b * C_ + c] = ld[4] + ld[5] + ld[6]  + ld[7];
        sqs [b * C_ + c] = ld[8] + ld[9] + ld[10] + ld[11];
    }
}

// ---- k4: MLP gate + fold instance-norm stats into (A,D): out = A*x + D
__global__ __launch_bounds__(256) void k4_mlp(
    const float* __restrict__ ctx, const float* __restrict__ w1, const float* __restrict__ b1,
    const float* __restrict__ ln_g, const float* __restrict__ ln_b,
    const float* __restrict__ w2, const float* __restrict__ b2,
    const float* __restrict__ sums, const float* __restrict__ sqs,
    float* __restrict__ Ab, float* __restrict__ Db)
{
    __shared__ float cs[C_];
    __shared__ float tl[CR_];
    const int b = blockIdx.x, t = threadIdx.x;
    cs[t]       = ctx[b * C_ + t];
    cs[t + 256] = ctx[b * C_ + t + 256];
    __syncthreads();

    const int row = t >> 3, sub = t & 7;
    float p = 0.f;
#pragma unroll 8
    for (int k = 0; k < 64; ++k) {
        const int c = sub + (k << 3);
        p += cs[c] * w1[row * C_ + c];
    }
    p += __shfl_down(p, 4, 8);
    p += __shfl_down(p, 2, 8);
    p += __shfl_down(p, 1, 8);
    if (sub == 0) tl[row] = p + b1[row];
    __syncthreads();

    float tn = 0.f;
    if (t < CR_) {
        float mu = 0.f;
#pragma unroll
        for (int i = 0; i < CR_; ++i) mu += tl[i];
        mu *= (1.f / CR_);
        float var = 0.f;
#pragma unroll
        for (int i = 0; i < CR_; ++i) { const float d = tl[i] - mu; var += d * d; }
        var *= (1.f / CR_);
        tn = (tl[t] - mu) * rsqrtf(var + EPSV) * ln_g[t] + ln_b[t];
        tn = fmaxf(tn, 0.f);
    }
    __syncthreads();
    if (t < CR_) tl[t] = tn;
    __syncthreads();

#pragma unroll
    for (int r = 0; r < 2; ++r) {
        const int c = t + r * 256;
        float g = b2[c];
#pragma unroll
        for (int i = 0; i < CR_; ++i) g += tl[i] * w2[c * CR_ + i];
        g = 1.f / (1.f + expf(-g));
        const float m  = sums[b * C_ + c] * (1.f / HW_);
        const float v  = sqs [b * C_ + c] * (1.f / HW_) - m * m;
        const float rn = rsqrtf(v + EPSV);
        Ab[b * C_ + c] = g + (1.f - g) * rn;
        Db[b * C_ + c] = -(1.f - g) * rn * m;
    }
}

// ---- k5: out = A*x + D
__global__ __launch_bounds__(256) void k5_apply(
    const float* __restrict__ x, const float* __restrict__ Ab, const float* __restrict__ Db,
    float* __restrict__ out)
{
    const int b = blockIdx.y, c = blockIdx.x, t = threadIdx.x;
    const size_t base = (size_t)(b * C_ + c) * HW_;
    const float a = Ab[b * C_ + c], d = Db[b * C_ + c];
    const float4* px = reinterpret_cast<const float4*>(x + base);
    float4*       po = reinterpret_cast<float4*>(out + base);
#pragma unroll
    for (int k = 0; k < 4; ++k) {
        const float4 v = px[t + 256 * k];
        po[t + 256 * k] = make_float4(fmaf(a, v.x, d), fmaf(a, v.y, d),
                                      fmaf(a, v.z, d), fmaf(a, v.w, d));
    }
}

extern "C" void kernel_launch(void* const* d_in, const int* in_sizes, int n_in,
                              void* d_out, int out_size, void* d_ws, size_t ws_size,
                              hipStream_t stream)
{
    const float* x      = (const float*)d_in[0];
    const float* w_mask = (const float*)d_in[1];
    // d_in[2] = b_mask: constant shift, cancels in softmax
    const float* w1     = (const float*)d_in[3];
    const float* b1     = (const float*)d_in[4];
    const float* ln_g   = (const float*)d_in[5];
    const float* ln_b   = (const float*)d_in[6];
    const float* w2     = (const float*)d_in[7];
    const float* b2     = (const float*)d_in[8];
    float* out = (float*)d_out;

    float* ws      = (float*)d_ws;
    float* partial = ws;                               // B*NCH*HW = 2M floats (8 MB)
    float* logits  = partial + (size_t)B_ * NCH * HW_; // B*HW
    float* attn    = logits + B_ * HW_;                // B*HW
    float* sums    = attn   + B_ * HW_;                // B*C
    float* sqs     = sums   + B_ * C_;                 // B*C
    float* ctx     = sqs    + B_ * C_;                 // B*C
    float* Ab      = ctx    + B_ * C_;                 // B*C
    float* Db      = Ab     + B_ * C_;                 // B*C

    k1_logits_partial<<<dim3(NCH, B_), 256, 0, stream>>>(x, w_mask, partial);
    k2a_reduce<<<dim3(HW_ / 1024, B_), 256, 0, stream>>>(partial, logits);
    k2b_softmax<<<B_, 256, 0, stream>>>(logits, attn);
    k3_context_stats<<<dim3(C_, B_), 256, 0, stream>>>(x, attn, ctx, sums, sqs);
    k4_mlp<<<B_, 256, 0, stream>>>(ctx, w1, b1, ln_g, ln_b, w2, b2, sums, sqs, Ab, Db);
    k5_apply<<<dim3(C_, B_), 256, 0, stream>>>(x, Ab, Db, out);
}

// Round 4
// 181.911 us; speedup vs baseline: 2.4559x; 1.0943x over previous
//
#include <hip/hip_runtime.h>
#include <math.h>

#define B_   32
#define C_   512
#define CR_  32
#define HW_  4096
#define NCH  16           // channel chunks
#define CPB  (C_/NCH)     // 32 channels per chunk
#define EPSV 1e-5f

typedef float v4f __attribute__((ext_vector_type(4)));

// ---- k1: partial logits. partial[b][ch][s] = sum_{c in chunk} w[c]*x[b,c,s]
// grid (NCH, B, 2): z splits the spatial range. 1024 blocks, 2 float4/thread/channel.
__global__ __launch_bounds__(256) void k1_logits_partial(
    const float* __restrict__ x, const float* __restrict__ w_mask,
    float* __restrict__ partial)
{
    const int b = blockIdx.y, ch = blockIdx.x, t = threadIdx.x;
    const int s0 = blockIdx.z * 512;            // float4 offset of this half
    const int c0 = ch * CPB;
    float4 a0 = {0,0,0,0}, a1 = {0,0,0,0};
#pragma unroll 4
    for (int cc = 0; cc < CPB; ++cc) {
        const float w = w_mask[c0 + cc];
        const float4* px = reinterpret_cast<const float4*>(x + (size_t)(b * C_ + c0 + cc) * HW_) + s0;
        float4 v;
        v = px[t      ]; a0.x += w*v.x; a0.y += w*v.y; a0.z += w*v.z; a0.w += w*v.w;
        v = px[t + 256]; a1.x += w*v.x; a1.y += w*v.y; a1.z += w*v.z; a1.w += w*v.w;
    }
    float4* pp = reinterpret_cast<float4*>(partial + (size_t)(b * NCH + ch) * HW_) + s0;
    pp[t      ] = a0;
    pp[t + 256] = a1;
}

// ---- k2: fused partial-reduce + softmax over HW per batch
__global__ __launch_bounds__(256) void k2_softmax(
    const float* __restrict__ partial, float* __restrict__ attn)
{
    __shared__ float l4[4];
    __shared__ float sM, sZ;
    const int b = blockIdx.x, t = threadIdx.x;
    const int lane = t & 63, wid = t >> 6;
    float4 v[4];
#pragma unroll
    for (int k = 0; k < 4; ++k) {
        float4 s = {0,0,0,0};
        const int i = t + 256 * k;
#pragma unroll
        for (int ch = 0; ch < NCH; ++ch) {
            const float4 p = reinterpret_cast<const float4*>(partial + (size_t)(b * NCH + ch) * HW_)[i];
            s.x += p.x; s.y += p.y; s.z += p.z; s.w += p.w;
        }
        v[k] = s;
    }
    float mx = -3.0e38f;
#pragma unroll
    for (int k = 0; k < 4; ++k)
        mx = fmaxf(mx, fmaxf(fmaxf(v[k].x, v[k].y), fmaxf(v[k].z, v[k].w)));
#pragma unroll
    for (int o = 32; o > 0; o >>= 1) mx = fmaxf(mx, __shfl_down(mx, o));
    if (lane == 0) l4[wid] = mx;
    __syncthreads();
    if (t == 0) sM = fmaxf(fmaxf(l4[0], l4[1]), fmaxf(l4[2], l4[3]));
    __syncthreads();
    const float M = sM;
    float e[16];
    float sum = 0.f;
#pragma unroll
    for (int k = 0; k < 4; ++k) {
        e[k*4+0] = expf(v[k].x - M);
        e[k*4+1] = expf(v[k].y - M);
        e[k*4+2] = expf(v[k].z - M);
        e[k*4+3] = expf(v[k].w - M);
        sum += e[k*4+0] + e[k*4+1] + e[k*4+2] + e[k*4+3];
    }
#pragma unroll
    for (int o = 32; o > 0; o >>= 1) sum += __shfl_down(sum, o);
    __syncthreads();
    if (lane == 0) l4[wid] = sum;
    __syncthreads();
    if (t == 0) sZ = l4[0] + l4[1] + l4[2] + l4[3];
    __syncthreads();
    const float rz = 1.f / sZ;
    float4* pa = reinterpret_cast<float4*>(attn + (size_t)b * HW_);
#pragma unroll
    for (int k = 0; k < 4; ++k)
        pa[t + 256 * k] = make_float4(e[k*4+0]*rz, e[k*4+1]*rz, e[k*4+2]*rz, e[k*4+3]*rz);
}

// ---- k3: context + instance-norm stats in one sweep of x[b,c,:]
__global__ __launch_bounds__(256) void k3_context_stats(
    const float* __restrict__ x, const float* __restrict__ attn,
    float* __restrict__ ctx, float* __restrict__ sums, float* __restrict__ sqs)
{
    __shared__ float ld[12];
    const int b = blockIdx.y, c = blockIdx.x, t = threadIdx.x;
    const int lane = t & 63, wid = t >> 6;
    const float4* px = reinterpret_cast<const float4*>(x + (size_t)(b * C_ + c) * HW_);
    const float4* pa = reinterpret_cast<const float4*>(attn + (size_t)b * HW_);
    float dot = 0.f, sm = 0.f, sq = 0.f;
#pragma unroll
    for (int k = 0; k < 4; ++k) {
        const float4 xv = px[t + 256 * k];
        const float4 av = pa[t + 256 * k];
        dot += xv.x*av.x + xv.y*av.y + xv.z*av.z + xv.w*av.w;
        sm  += xv.x + xv.y + xv.z + xv.w;
        sq  += xv.x*xv.x + xv.y*xv.y + xv.z*xv.z + xv.w*xv.w;
    }
#pragma unroll
    for (int o = 32; o > 0; o >>= 1) {
        dot += __shfl_down(dot, o);
        sm  += __shfl_down(sm, o);
        sq  += __shfl_down(sq, o);
    }
    if (lane == 0) { ld[wid] = dot; ld[4 + wid] = sm; ld[8 + wid] = sq; }
    __syncthreads();
    if (t == 0) {
        ctx [b * C_ + c] = ld[0] + ld[1] + ld[2]  + ld[3];
        sums[b * C_ + c] = ld[4] + ld[5] + ld[6]  + ld[7];
        sqs [b * C_ + c] = ld[8] + ld[9] + ld[10] + ld[11];
    }
}

// ---- k4: MLP gate + fold instance-norm stats into (A,D): out = A*x + D
__global__ __launch_bounds__(256) void k4_mlp(
    const float* __restrict__ ctx, const float* __restrict__ w1, const float* __restrict__ b1,
    const float* __restrict__ ln_g, const float* __restrict__ ln_b,
    const float* __restrict__ w2, const float* __restrict__ b2,
    const float* __restrict__ sums, const float* __restrict__ sqs,
    float* __restrict__ Ab, float* __restrict__ Db)
{
    __shared__ float cs[C_];
    __shared__ float tl[CR_];
    const int b = blockIdx.x, t = threadIdx.x;
    cs[t]       = ctx[b * C_ + t];
    cs[t + 256] = ctx[b * C_ + t + 256];
    __syncthreads();

    const int row = t >> 3, sub = t & 7;
    float p = 0.f;
#pragma unroll 8
    for (int k = 0; k < 64; ++k) {
        const int c = sub + (k << 3);
        p += cs[c] * w1[row * C_ + c];
    }
    p += __shfl_down(p, 4, 8);
    p += __shfl_down(p, 2, 8);
    p += __shfl_down(p, 1, 8);
    if (sub == 0) tl[row] = p + b1[row];
    __syncthreads();

    float tn = 0.f;
    if (t < CR_) {
        float mu = 0.f;
#pragma unroll
        for (int i = 0; i < CR_; ++i) mu += tl[i];
        mu *= (1.f / CR_);
        float var = 0.f;
#pragma unroll
        for (int i = 0; i < CR_; ++i) { const float d = tl[i] - mu; var += d * d; }
        var *= (1.f / CR_);
        tn = (tl[t] - mu) * rsqrtf(var + EPSV) * ln_g[t] + ln_b[t];
        tn = fmaxf(tn, 0.f);
    }
    __syncthreads();
    if (t < CR_) tl[t] = tn;
    __syncthreads();

#pragma unroll
    for (int r = 0; r < 2; ++r) {
        const int c = t + r * 256;
        float g = b2[c];
#pragma unroll
        for (int i = 0; i < CR_; ++i) g += tl[i] * w2[c * CR_ + i];
        g = 1.f / (1.f + expf(-g));
        const float m  = sums[b * C_ + c] * (1.f / HW_);
        const float v  = sqs [b * C_ + c] * (1.f / HW_) - m * m;
        const float rn = rsqrtf(v + EPSV);
        Ab[b * C_ + c] = g + (1.f - g) * rn;
        Db[b * C_ + c] = -(1.f - g) * rn * m;
    }
}

// ---- k5: out = A*x + D (non-temporal stores: out is never re-read)
__global__ __launch_bounds__(256) void k5_apply(
    const float* __restrict__ x, const float* __restrict__ Ab, const float* __restrict__ Db,
    float* __restrict__ out)
{
    const int b = blockIdx.y, c = blockIdx.x, t = threadIdx.x;
    const size_t base = (size_t)(b * C_ + c) * HW_;
    const float a = Ab[b * C_ + c], d = Db[b * C_ + c];
    const float4* px = reinterpret_cast<const float4*>(x + base);
    v4f*          po = reinterpret_cast<v4f*>(out + base);
#pragma unroll
    for (int k = 0; k < 4; ++k) {
        const float4 v = px[t + 256 * k];
        v4f r;
        r.x = fmaf(a, v.x, d); r.y = fmaf(a, v.y, d);
        r.z = fmaf(a, v.z, d); r.w = fmaf(a, v.w, d);
        __builtin_nontemporal_store(r, po + t + 256 * k);
    }
}

extern "C" void kernel_launch(void* const* d_in, const int* in_sizes, int n_in,
                              void* d_out, int out_size, void* d_ws, size_t ws_size,
                              hipStream_t stream)
{
    const float* x      = (const float*)d_in[0];
    const float* w_mask = (const float*)d_in[1];
    // d_in[2] = b_mask: constant shift, cancels in softmax
    const float* w1     = (const float*)d_in[3];
    const float* b1     = (const float*)d_in[4];
    const float* ln_g   = (const float*)d_in[5];
    const float* ln_b   = (const float*)d_in[6];
    const float* w2     = (const float*)d_in[7];
    const float* b2     = (const float*)d_in[8];
    float* out = (float*)d_out;

    float* ws      = (float*)d_ws;
    float* partial = ws;                               // B*NCH*HW = 2M floats (8 MB)
    float* attn    = partial + (size_t)B_ * NCH * HW_; // B*HW
    float* sums    = attn   + B_ * HW_;                // B*C
    float* sqs     = sums   + B_ * C_;                 // B*C
    float* ctx     = sqs    + B_ * C_;                 // B*C
    float* Ab      = ctx    + B_ * C_;                 // B*C
    float* Db      = Ab     + B_ * C_;                 // B*C

    k1_logits_partial<<<dim3(NCH, B_, 2), 256, 0, stream>>>(x, w_mask, partial);
    k2_softmax<<<B_, 256, 0, stream>>>(partial, attn);
    k3_context_stats<<<dim3(C_, B_), 256, 0, stream>>>(x, attn, ctx, sums, sqs);
    k4_mlp<<<B_, 256, 0, stream>>>(ctx, w1, b1, ln_g, ln_b, w2, b2, sums, sqs, Ab, Db);
    k5_apply<<<dim3(C_, B_), 256, 0, stream>>>(x, Ab, Db, out);
}